// Round 24
// baseline (53.718 us; speedup 1.0000x reference)
//
#include <hip/hip_runtime.h>

#define N_IN   16384
#define N_OUT  16384
#define NE     300000
#define SEGS   8           // segments per gather window
#define NWIN   (N_OUT / SEGS)
#define GRID_G 1024        // balanced: exactly 2 windows/block, 4 blocks/CU
#define BKG    128         // u16 stride per k-group (unpadded -> LDS 40960 = 4 blk/CU)
#define BSTR   512         // u16 per b per buffer = 4 * BKG
#define SROW   256         // u16 per S_lds row (swizzled, no pad)
#define NCHK   9375        // NE / 32 exactly

// k_front block roles
#define MLPB   586
#define TRB    1024
#define SETB   80

typedef unsigned int   u32;
typedef unsigned short u16;
typedef __attribute__((ext_vector_type(4))) float f32x4;
typedef __attribute__((ext_vector_type(8))) short bf16x8;

// round-to-nearest-even fp32 -> bf16 bits
__device__ __forceinline__ u16 f2bf(float x) {
    union { float f; u32 u; } v; v.f = x;
    u32 r = v.u + 0x7fffu + ((v.u >> 16) & 1u);
    return (u16)(r >> 16);
}

__device__ __forceinline__ float fast_sin(float t) {
    float r;
    asm("v_sin_f32 %0, %1" : "=v"(r) : "v"(t * 0.15915494309189535f));
    return r;
}

// ---------------------------------------------------------------------------
// Kernel 1: fused front end (R21-verified, unchanged).
// ---------------------------------------------------------------------------
__global__ __launch_bounds__(256) void k_front(
        const float* __restrict__ pin, const float* __restrict__ pout,
        const float* __restrict__ wts, const int* __restrict__ ei,
        const float* __restrict__ W0, const float* __restrict__ W1,
        const float* __restrict__ W2, const float* __restrict__ W3,
        const float* __restrict__ W4, const float* __restrict__ W5,
        const float* __restrict__ feat,
        u16* __restrict__ ftb, u16* __restrict__ hB,
        int* __restrict__ segoff, u16* __restrict__ Bfrag) {
    __shared__ float tile[32][33];
    int tid = threadIdx.x, bid = blockIdx.x;

    if (bid < MLPB) {
        int e0 = (bid * 256 + tid) * 2;
        if (e0 >= NE) return;
        int4 q = *(const int4*)(ei + e0 * 2);   // (out0,in0,out1,in1)
        float2 po0 = ((const float2*)pout)[q.x];
        float2 pi0 = ((const float2*)pin)[q.y];
        float2 po1 = ((const float2*)pout)[q.z];
        float2 pi1 = ((const float2*)pin)[q.w];
        float x0 = po0.x - pi0.x, y0 = po0.y - pi0.y;
        float x1 = po1.x - pi1.x, y1 = po1.y - pi1.y;

        float h0[16], h1[16];
#pragma unroll
        for (int j = 0; j < 16; ++j) {
            float wa = W0[j], wb = W0[16 + j];          // uniform -> s_load
            h0[j] = fast_sin(x0 * wa + y0 * wb);
            h1[j] = fast_sin(x1 * wa + y1 * wb);
        }
#pragma unroll
        for (int L = 0; L < 4; ++L) {
            const float* W = (L == 0) ? W1 : (L == 1) ? W2 : (L == 2) ? W3 : W4;
            float n0[16], n1[16];
#pragma unroll
            for (int j = 0; j < 16; ++j) {
                float a0 = 0.f, a1 = 0.f;
#pragma unroll
                for (int i = 0; i < 16; ++i) {
                    float w = W[i * 16 + j];            // uniform -> s_load
                    a0 = fmaf(h0[i], w, a0);
                    a1 = fmaf(h1[i], w, a1);
                }
                n0[j] = fast_sin(a0); n1[j] = fast_sin(a1);
            }
#pragma unroll
            for (int j = 0; j < 16; ++j) { h0[j] = n0[j]; h1[j] = n1[j]; }
        }
        float we0 = wts[q.y], we1 = wts[q.w];
        u16* hp = hB + ((size_t)(e0 >> 5)) * 512 + (e0 & 31);
#pragma unroll
        for (int j = 0; j < 16; ++j) {
            u32 pk = (u32)f2bf(we0 * h0[j]) | ((u32)f2bf(we1 * h1[j]) << 16);
            *(u32*)(hp + j * 32) = pk;
        }
    } else if (bid < MLPB + TRB) {
        int jb = (bid - MLPB) * 2;
        int tx = tid & 31, ty = tid >> 5;
#pragma unroll
        for (int t = 0; t < 2; ++t) {
            int job = jb + t;
            int n0 = (job & 511) * 32, c0 = (job >> 9) * 32;
#pragma unroll
            for (int k = 0; k < 4; ++k)
                tile[ty + k * 8][tx] = feat[(size_t)(c0 + ty + k * 8) * N_IN + n0 + tx];
            __syncthreads();
#pragma unroll
            for (int k = 0; k < 4; ++k)
                ftb[(size_t)(n0 + ty + k * 8) * 128 + c0 + tx] = f2bf(tile[tx][ty + k * 8]);
            __syncthreads();
        }
    } else {
        int g = (bid - MLPB - TRB) * 256 + tid;
        if (g <= N_OUT) {
            if (g == N_OUT) segoff[g] = NE;
            else {
                int lo = 0, hi = NE;
                while (lo < hi) { int m = (lo + hi) >> 1; if (ei[2 * m] < g) lo = m + 1; else hi = m; }
                segoff[g] = lo;
            }
        }
        if (g < 4096) {
            int ks = g >> 9, rem = g & 511, l = rem >> 3, e = rem & 7;
            int k = ks * 32 + ((l >> 4) << 3) + e;
            int o = l & 15;
            Bfrag[g] = f2bf(W5[(k >> 4) * 256 + ((k & 15) << 4) + o]);
        }
    }
}

// ---------------------------------------------------------------------------
// Kernel 2: fused MFMA gather + projection. R24 = R23 compact body with
// balanced grid: GRID_G=1024 (exactly 2 windows/block), BKG=128 (unpadded
// stage tile -> LDS 40960 B -> 4 blocks/CU), __launch_bounds__(256,4).
// ---------------------------------------------------------------------------
#define EIW(IA, IB, BSE) do {                                             \
    int g_ = (BSE) + 2 * pr; g_ = g_ <= NE - 2 ? g_ : NE - 2;             \
    int4 q_ = *(const int4*)(ei + 2 * g_); IA = q_.y; IB = q_.w; } while (0)

#define FTW(FA, FB, IA, IB) do {                                          \
    FA = ftb4[(size_t)(u32)(IA) * 16 + oct];                              \
    FB = ftb4[(size_t)(u32)(IB) * 16 + oct]; } while (0)

#define BQW(BQ, BSE) do {                                                 \
    int ch_ = (BSE) >> 5; ch_ = ch_ <= NCHK - 1 ? ch_ : NCHK - 1;         \
    BQ = *(const bf16x8*)(hB + (size_t)ch_ * 512 + (j << 5) + (kg << 3)); } while (0)

// v_perm_b32 pack (R23-verified)
#define STGW(FA, FB) do {                                                 \
    u32 aw_[4] = {FA.x, FA.y, FA.z, FA.w};                                \
    u32 bw_[4] = {FB.x, FB.y, FB.z, FB.w};                                \
    int wb_ = bloc * BSTR + (pr >> 2) * BKG + 2 * (pr & 3);               \
    _Pragma("unroll")                                                     \
    for (int h_ = 0; h_ < 4; ++h_) {                                      \
        u32 lo_ = __builtin_amdgcn_perm(bw_[h_], aw_[h_], 0x05040100u);   \
        u32 hi_ = __builtin_amdgcn_perm(bw_[h_], aw_[h_], 0x07060302u);   \
        *(u32*)&stW[wb_ + (ibase + 2 * h_) * 8] = lo_;                    \
        *(u32*)&stW[wb_ + (ibase + 2 * h_ + 1) * 8] = hi_;                \
    } } while (0)

// always-masked PIECE (runtime bounds)
#define PIECEM(KLO, KHI) do {                                             \
    bf16x8 bm_;                                                           \
    _Pragma("unroll")                                                     \
    for (int e_ = 0; e_ < 8; ++e_) {                                      \
        int k_ = kg * 8 + e_;                                             \
        bm_[e_] = (k_ >= (KLO) && k_ < (KHI)) ? bqC[e_] : (short)0;       \
    }                                                                     \
    acc0 = __builtin_amdgcn_mfma_f32_16x16x32_bf16(a0, bm_, acc0, 0, 0, 0); \
    acc1 = __builtin_amdgcn_mfma_f32_16x16x32_bf16(a1, bm_, acc1, 0, 0, 0); \
} while (0)

// swizzled DUMP (R21-verified, f2bf): chunk c = j*2+(kg>>1); phys = (c+row)&31
#define DUMP(SS) do {                                                     \
    int c_ = j * 2 + (kg >> 1);                                           \
    int r0_ = b0 * SEGS + (SS);                                           \
    int r1_ = r0_ + SEGS;                                                 \
    u32 l0_ = (u32)f2bf(acc0[0]) | ((u32)f2bf(acc0[1]) << 16);            \
    u32 l1_ = (u32)f2bf(acc0[2]) | ((u32)f2bf(acc0[3]) << 16);            \
    *(uint2*)&S_lds[r0_ * 256 + (((c_ + r0_) & 31) << 3) + ((kg & 1) << 2)] = \
        make_uint2(l0_, l1_);                                             \
    u32 l2_ = (u32)f2bf(acc1[0]) | ((u32)f2bf(acc1[1]) << 16);            \
    u32 l3_ = (u32)f2bf(acc1[2]) | ((u32)f2bf(acc1[3]) << 16);            \
    *(uint2*)&S_lds[r1_ * 256 + (((c_ + r1_) & 31) << 3) + ((kg & 1) << 2)] = \
        make_uint2(l2_, l3_);                                             \
    acc0 = (f32x4){0.f, 0.f, 0.f, 0.f}; acc1 = (f32x4){0.f, 0.f, 0.f, 0.f}; \
} while (0)

__global__ __launch_bounds__(256, 4) void k_gather(
        const int* __restrict__ ei, const u16* __restrict__ ftb,
        const u16* __restrict__ hB, const int* __restrict__ segoff,
        const u16* __restrict__ Bfrag, float* __restrict__ out)
{
    __shared__ __align__(16) u16 stA[4 * 2 * BSTR];      //  8192 B (single buf)
    __shared__ __align__(16) u16 S_lds[8 * SEGS * SROW]; // 32768 B (swizzled)

    int tid = threadIdx.x, lane = tid & 63, wave = tid >> 6;
    int b0 = wave * 2;
    int pr = lane >> 2, c4 = lane & 3;
    int bloc = c4 >> 1, ibase = (c4 & 1) * 8;
    int oct = b0 * 2 + c4;
    int j = lane & 15, kg = lane >> 4;
    u16* stW = stA + wave * (2 * BSTR);
    const uint4* ftb4 = (const uint4*)ftb;

    // proj B-fragments hoisted across all windows
    bf16x8 bfr[8];
#pragma unroll
    for (int ks = 0; ks < 8; ++ks)
        bfr[ks] = *(const bf16x8*)(Bfrag + ks * 512 + lane * 8);

    for (int w = blockIdx.x; w < NWIN; w += GRID_G) {
        int s0 = w * SEGS;

        // per-lane segment offsets (lanes 0..8 hold segoff[s0..s0+8])
        int segv = segoff[s0 + (lane <= SEGS ? lane : SEGS)];
        int e0 = __shfl(segv, 0), e1 = __shfl(segv, SEGS);

        int base0 = e0 & ~31;
        int nc = (e1 - base0 + 31) >> 5;

        f32x4 acc0 = {0.f, 0.f, 0.f, 0.f}, acc1 = {0.f, 0.f, 0.f, 0.f};

        if (nc > 0) {
            int eiA, eiB;
            uint4 faA, fbA, faB, fbB;
            bf16x8 bqC, bqN, bqL;
            // prologue (R13): chunk0 -> B -> staged; chunk1 -> A; chunk2 -> B
            EIW(eiA, eiB, base0);        FTW(faB, fbB, eiA, eiB);
            BQW(bqC, base0);
            EIW(eiA, eiB, base0 + 32);   FTW(faA, fbA, eiA, eiB);
            BQW(bqN, base0 + 32);
            STGW(faB, fbB);                           // stage chunk 0
            EIW(eiA, eiB, base0 + 64);   FTW(faB, fbB, eiA, eiB);
            BQW(bqL, base0 + 64);
            EIW(eiA, eiB, base0 + 96);

            int s = 0, klo = e0 - base0;
#pragma unroll 1
            for (int c = 0; c < nc; ++c) {
                int base_ = base0 + 32 * c, ce_ = base_ + 32;
                bf16x8 a0 = *(const bf16x8*)&stW[(lane >> 4) * BKG + (lane & 15) * 8];
                bf16x8 a1 = *(const bf16x8*)&stW[BSTR + (lane >> 4) * BKG + (lane & 15) * 8];
                STGW(faA, fbA);                  // stage chunk c+1 (after reads)
                FTW(faA, fbA, eiA, eiB);         // load chunk c+3 -> A-set
                int eiA2, eiB2; EIW(eiA2, eiB2, base_ + 128);
                bf16x8 bqT; BQW(bqT, base_ + 96);

                // dynamic segment sweep (R7-proven shfl while)
                int nxt = __shfl(segv, s + 1 <= SEGS ? s + 1 : SEGS);
                while (s < SEGS && nxt <= ce_) {
                    int khi = nxt - base_;
                    if (khi > klo) PIECEM(klo, khi);
                    DUMP(s);
                    ++s; klo = khi;
                    nxt = __shfl(segv, s + 1 <= SEGS ? s + 1 : SEGS);
                }
                if (s < SEGS && klo < 32) PIECEM(klo, 32);
                klo = 0;

                // rotate register sets (A<->B) and pipeline regs
                uint4 t_;
                t_ = faA; faA = faB; faB = t_;
                t_ = fbA; fbA = fbB; fbB = t_;
                bqC = bqN; bqN = bqL; bqL = bqT;
                eiA = eiA2; eiB = eiB2;
            }
        } else {
            // zero this wave's 16 S rows (both b's)
            u32* zz = (u32*)&S_lds[wave * 4096];
            for (int I = lane; I < 2048; I += 64) zz[I] = 0;
        }

        // ---- projection epilogue (R13-verified): 16-row A-tile, both b's ----
        {
            int r = wave * 16 + (lane & 15);
            f32x4 ap = {0.f, 0.f, 0.f, 0.f};
#pragma unroll
            for (int ks = 0; ks < 8; ++ks) {
                bf16x8 af = *(const bf16x8*)
                    &S_lds[r * 256 + (((ks * 4 + kg + r) & 31) << 3)];
                ap = __builtin_amdgcn_mfma_f32_16x16x32_bf16(af, bfr[ks], ap, 0, 0, 0);
            }
            int o = lane & 15;
            int b = b0 + (kg >> 1);
            *(float4*)(out + (((size_t)(b * 16 + o)) << 14) + s0 + ((kg & 1) << 2)) =
                make_float4(ap[0], ap[1], ap[2], ap[3]);
        }
    }
}

// ---------------------------------------------------------------------------
extern "C" void kernel_launch(void* const* d_in, const int* in_sizes, int n_in,
                              void* d_out, int out_size, void* d_ws, size_t ws_size,
                              hipStream_t stream) {
    const float* pin  = (const float*)d_in[0];
    const float* pout = (const float*)d_in[1];
    const float* wts  = (const float*)d_in[2];
    const float* feat = (const float*)d_in[3];
    const int*   ei   = (const int*)d_in[4];
    const float* W0   = (const float*)d_in[5];
    const float* W1   = (const float*)d_in[6];
    const float* W2   = (const float*)d_in[7];
    const float* W3   = (const float*)d_in[8];
    const float* W4   = (const float*)d_in[9];
    const float* W5   = (const float*)d_in[10];
    float* out = (float*)d_out;

    u16* ftb    = (u16*)d_ws;                             // 4,194,304 B
    u16* hB     = ftb + (size_t)N_IN * 128;               // 9,600,000 B
    int* segoff = (int*)(hB + (size_t)NCHK * 512 + 64);   // 65,552 B
    u16* Bfrag  = (u16*)(segoff + 16388);                 // 8,192 B

    k_front<<<MLPB + TRB + SETB, 256, 0, stream>>>(
        pin, pout, wts, ei, W0, W1, W2, W3, W4, W5, feat,
        ftb, hB, segoff, Bfrag);
    k_gather<<<GRID_G, 256, 0, stream>>>(ei, ftb, hB, segoff, Bfrag, out);
}

// Round 25
// 49.217 us; speedup vs baseline: 1.0914x; 1.0914x over previous
//
#include <hip/hip_runtime.h>

#define N_IN   16384
#define N_OUT  16384
#define NE     300000
#define SEGS   8           // segments per gather window
#define NWIN   (N_OUT / SEGS)
#define GRID_G 768         // persistent gather grid (3 blocks/CU)
#define BKG    136         // u16 stride per k-group in stage tile (128 + 8 pad)
#define BSTR   544         // u16 per b per (single) buffer = 4 * BKG
#define SROW   256         // u16 per S_lds row (swizzled, no pad)
#define NCHK   9375        // NE / 32 exactly

// k_front block roles
#define MLPB   586
#define TRB    1024
#define SETB   80

typedef unsigned int   u32;
typedef unsigned short u16;
typedef __attribute__((ext_vector_type(4))) float f32x4;
typedef __attribute__((ext_vector_type(8))) short bf16x8;

// round-to-nearest-even fp32 -> bf16 bits
__device__ __forceinline__ u16 f2bf(float x) {
    union { float f; u32 u; } v; v.f = x;
    u32 r = v.u + 0x7fffu + ((v.u >> 16) & 1u);
    return (u16)(r >> 16);
}

__device__ __forceinline__ float fast_sin(float t) {
    float r;
    asm("v_sin_f32 %0, %1" : "=v"(r) : "v"(t * 0.15915494309189535f));
    return r;
}

// ---------------------------------------------------------------------------
// Kernel 1: fused front end (verified).
// ---------------------------------------------------------------------------
__global__ __launch_bounds__(256) void k_front(
        const float* __restrict__ pin, const float* __restrict__ pout,
        const float* __restrict__ wts, const int* __restrict__ ei,
        const float* __restrict__ W0, const float* __restrict__ W1,
        const float* __restrict__ W2, const float* __restrict__ W3,
        const float* __restrict__ W4, const float* __restrict__ W5,
        const float* __restrict__ feat,
        u16* __restrict__ ftb, u16* __restrict__ hB,
        int* __restrict__ segoff, u16* __restrict__ Bfrag) {
    __shared__ float tile[32][33];
    int tid = threadIdx.x, bid = blockIdx.x;

    if (bid < MLPB) {
        int e0 = (bid * 256 + tid) * 2;
        if (e0 >= NE) return;
        int4 q = *(const int4*)(ei + e0 * 2);   // (out0,in0,out1,in1)
        float2 po0 = ((const float2*)pout)[q.x];
        float2 pi0 = ((const float2*)pin)[q.y];
        float2 po1 = ((const float2*)pout)[q.z];
        float2 pi1 = ((const float2*)pin)[q.w];
        float x0 = po0.x - pi0.x, y0 = po0.y - pi0.y;
        float x1 = po1.x - pi1.x, y1 = po1.y - pi1.y;

        float h0[16], h1[16];
#pragma unroll
        for (int j = 0; j < 16; ++j) {
            float wa = W0[j], wb = W0[16 + j];          // uniform -> s_load
            h0[j] = fast_sin(x0 * wa + y0 * wb);
            h1[j] = fast_sin(x1 * wa + y1 * wb);
        }
#pragma unroll
        for (int L = 0; L < 4; ++L) {
            const float* W = (L == 0) ? W1 : (L == 1) ? W2 : (L == 2) ? W3 : W4;
            float n0[16], n1[16];
#pragma unroll
            for (int j = 0; j < 16; ++j) {
                float a0 = 0.f, a1 = 0.f;
#pragma unroll
                for (int i = 0; i < 16; ++i) {
                    float w = W[i * 16 + j];            // uniform -> s_load
                    a0 = fmaf(h0[i], w, a0);
                    a1 = fmaf(h1[i], w, a1);
                }
                n0[j] = fast_sin(a0); n1[j] = fast_sin(a1);
            }
#pragma unroll
            for (int j = 0; j < 16; ++j) { h0[j] = n0[j]; h1[j] = n1[j]; }
        }
        float we0 = wts[q.y], we1 = wts[q.w];
        u16* hp = hB + ((size_t)(e0 >> 5)) * 512 + (e0 & 31);
#pragma unroll
        for (int j = 0; j < 16; ++j) {
            u32 pk = (u32)f2bf(we0 * h0[j]) | ((u32)f2bf(we1 * h1[j]) << 16);
            *(u32*)(hp + j * 32) = pk;
        }
    } else if (bid < MLPB + TRB) {
        int jb = (bid - MLPB) * 2;
        int tx = tid & 31, ty = tid >> 5;
#pragma unroll
        for (int t = 0; t < 2; ++t) {
            int job = jb + t;
            int n0 = (job & 511) * 32, c0 = (job >> 9) * 32;
#pragma unroll
            for (int k = 0; k < 4; ++k)
                tile[ty + k * 8][tx] = feat[(size_t)(c0 + ty + k * 8) * N_IN + n0 + tx];
            __syncthreads();
#pragma unroll
            for (int k = 0; k < 4; ++k)
                ftb[(size_t)(n0 + ty + k * 8) * 128 + c0 + tx] = f2bf(tile[tx][ty + k * 8]);
            __syncthreads();
        }
    } else {
        int g = (bid - MLPB - TRB) * 256 + tid;
        if (g <= N_OUT) {
            if (g == N_OUT) segoff[g] = NE;
            else {
                int lo = 0, hi = NE;
                while (lo < hi) { int m = (lo + hi) >> 1; if (ei[2 * m] < g) lo = m + 1; else hi = m; }
                segoff[g] = lo;
            }
        }
        if (g < 4096) {
            int ks = g >> 9, rem = g & 511, l = rem >> 3, e = rem & 7;
            int k = ks * 32 + ((l >> 4) << 3) + e;
            int o = l & 15;
            Bfrag[g] = f2bf(W5[(k >> 4) * 256 + ((k & 15) << 4) + o]);
        }
    }
}

// ---------------------------------------------------------------------------
// Kernel 2: fused MFMA gather + projection (R23-verified, session best).
// Compact rolled body + perm-STGW; persistent GRID_G=768; barrier-free;
// padded stage tile; swizzled S_lds (phys chunk = (c+row)&31).
// ---------------------------------------------------------------------------
#define EIW(IA, IB, BSE) do {                                             \
    int g_ = (BSE) + 2 * pr; g_ = g_ <= NE - 2 ? g_ : NE - 2;             \
    int4 q_ = *(const int4*)(ei + 2 * g_); IA = q_.y; IB = q_.w; } while (0)

#define FTW(FA, FB, IA, IB) do {                                          \
    FA = ftb4[(size_t)(u32)(IA) * 16 + oct];                              \
    FB = ftb4[(size_t)(u32)(IB) * 16 + oct]; } while (0)

#define BQW(BQ, BSE) do {                                                 \
    int ch_ = (BSE) >> 5; ch_ = ch_ <= NCHK - 1 ? ch_ : NCHK - 1;         \
    BQ = *(const bf16x8*)(hB + (size_t)ch_ * 512 + (j << 5) + (kg << 3)); } while (0)

// v_perm_b32 pack (R23-verified)
#define STGW(FA, FB) do {                                                 \
    u32 aw_[4] = {FA.x, FA.y, FA.z, FA.w};                                \
    u32 bw_[4] = {FB.x, FB.y, FB.z, FB.w};                                \
    int wb_ = bloc * BSTR + (pr >> 2) * BKG + 2 * (pr & 3);               \
    _Pragma("unroll")                                                     \
    for (int h_ = 0; h_ < 4; ++h_) {                                      \
        u32 lo_ = __builtin_amdgcn_perm(bw_[h_], aw_[h_], 0x05040100u);   \
        u32 hi_ = __builtin_amdgcn_perm(bw_[h_], aw_[h_], 0x07060302u);   \
        *(u32*)&stW[wb_ + (ibase + 2 * h_) * 8] = lo_;                    \
        *(u32*)&stW[wb_ + (ibase + 2 * h_ + 1) * 8] = hi_;                \
    } } while (0)

// always-masked PIECE (runtime bounds)
#define PIECEM(KLO, KHI) do {                                             \
    bf16x8 bm_;                                                           \
    _Pragma("unroll")                                                     \
    for (int e_ = 0; e_ < 8; ++e_) {                                      \
        int k_ = kg * 8 + e_;                                             \
        bm_[e_] = (k_ >= (KLO) && k_ < (KHI)) ? bqC[e_] : (short)0;       \
    }                                                                     \
    acc0 = __builtin_amdgcn_mfma_f32_16x16x32_bf16(a0, bm_, acc0, 0, 0, 0); \
    acc1 = __builtin_amdgcn_mfma_f32_16x16x32_bf16(a1, bm_, acc1, 0, 0, 0); \
} while (0)

// swizzled DUMP (verified): chunk c = j*2+(kg>>1); phys = (c+row)&31
#define DUMP(SS) do {                                                     \
    int c_ = j * 2 + (kg >> 1);                                           \
    int r0_ = b0 * SEGS + (SS);                                           \
    int r1_ = r0_ + SEGS;                                                 \
    u32 l0_ = (u32)f2bf(acc0[0]) | ((u32)f2bf(acc0[1]) << 16);            \
    u32 l1_ = (u32)f2bf(acc0[2]) | ((u32)f2bf(acc0[3]) << 16);            \
    *(uint2*)&S_lds[r0_ * 256 + (((c_ + r0_) & 31) << 3) + ((kg & 1) << 2)] = \
        make_uint2(l0_, l1_);                                             \
    u32 l2_ = (u32)f2bf(acc1[0]) | ((u32)f2bf(acc1[1]) << 16);            \
    u32 l3_ = (u32)f2bf(acc1[2]) | ((u32)f2bf(acc1[3]) << 16);            \
    *(uint2*)&S_lds[r1_ * 256 + (((c_ + r1_) & 31) << 3) + ((kg & 1) << 2)] = \
        make_uint2(l2_, l3_);                                             \
    acc0 = (f32x4){0.f, 0.f, 0.f, 0.f}; acc1 = (f32x4){0.f, 0.f, 0.f, 0.f}; \
} while (0)

__global__ __launch_bounds__(256, 3) void k_gather(
        const int* __restrict__ ei, const u16* __restrict__ ftb,
        const u16* __restrict__ hB, const int* __restrict__ segoff,
        const u16* __restrict__ Bfrag, float* __restrict__ out)
{
    __shared__ __align__(16) u16 stA[4 * 2 * BSTR];      //  8704 B (single buf)
    __shared__ __align__(16) u16 S_lds[8 * SEGS * SROW]; // 32768 B (swizzled)

    int tid = threadIdx.x, lane = tid & 63, wave = tid >> 6;
    int b0 = wave * 2;
    int pr = lane >> 2, c4 = lane & 3;
    int bloc = c4 >> 1, ibase = (c4 & 1) * 8;
    int oct = b0 * 2 + c4;
    int j = lane & 15, kg = lane >> 4;
    u16* stW = stA + wave * (2 * BSTR);
    const uint4* ftb4 = (const uint4*)ftb;

    // proj B-fragments hoisted across all windows
    bf16x8 bfr[8];
#pragma unroll
    for (int ks = 0; ks < 8; ++ks)
        bfr[ks] = *(const bf16x8*)(Bfrag + ks * 512 + lane * 8);

    for (int w = blockIdx.x; w < NWIN; w += GRID_G) {
        int s0 = w * SEGS;

        // per-lane segment offsets (lanes 0..8 hold segoff[s0..s0+8])
        int segv = segoff[s0 + (lane <= SEGS ? lane : SEGS)];
        int e0 = __shfl(segv, 0), e1 = __shfl(segv, SEGS);

        int base0 = e0 & ~31;
        int nc = (e1 - base0 + 31) >> 5;

        f32x4 acc0 = {0.f, 0.f, 0.f, 0.f}, acc1 = {0.f, 0.f, 0.f, 0.f};

        if (nc > 0) {
            int eiA, eiB;
            uint4 faA, fbA, faB, fbB;
            bf16x8 bqC, bqN, bqL;
            // prologue: chunk0 -> B -> staged; chunk1 -> A; chunk2 -> B
            EIW(eiA, eiB, base0);        FTW(faB, fbB, eiA, eiB);
            BQW(bqC, base0);
            EIW(eiA, eiB, base0 + 32);   FTW(faA, fbA, eiA, eiB);
            BQW(bqN, base0 + 32);
            STGW(faB, fbB);                           // stage chunk 0
            EIW(eiA, eiB, base0 + 64);   FTW(faB, fbB, eiA, eiB);
            BQW(bqL, base0 + 64);
            EIW(eiA, eiB, base0 + 96);

            int s = 0, klo = e0 - base0;
#pragma unroll 1
            for (int c = 0; c < nc; ++c) {
                int base_ = base0 + 32 * c, ce_ = base_ + 32;
                bf16x8 a0 = *(const bf16x8*)&stW[(lane >> 4) * BKG + (lane & 15) * 8];
                bf16x8 a1 = *(const bf16x8*)&stW[BSTR + (lane >> 4) * BKG + (lane & 15) * 8];
                STGW(faA, fbA);                  // stage chunk c+1 (after reads)
                FTW(faA, fbA, eiA, eiB);         // load chunk c+3 -> A-set
                int eiA2, eiB2; EIW(eiA2, eiB2, base_ + 128);
                bf16x8 bqT; BQW(bqT, base_ + 96);

                // dynamic segment sweep
                int nxt = __shfl(segv, s + 1 <= SEGS ? s + 1 : SEGS);
                while (s < SEGS && nxt <= ce_) {
                    int khi = nxt - base_;
                    if (khi > klo) PIECEM(klo, khi);
                    DUMP(s);
                    ++s; klo = khi;
                    nxt = __shfl(segv, s + 1 <= SEGS ? s + 1 : SEGS);
                }
                if (s < SEGS && klo < 32) PIECEM(klo, 32);
                klo = 0;

                // rotate register sets (A<->B) and pipeline regs
                uint4 t_;
                t_ = faA; faA = faB; faB = t_;
                t_ = fbA; fbA = fbB; fbB = t_;
                bqC = bqN; bqN = bqL; bqL = bqT;
                eiA = eiA2; eiB = eiB2;
            }
        } else {
            // zero this wave's 16 S rows (both b's)
            u32* zz = (u32*)&S_lds[wave * 4096];
            for (int I = lane; I < 2048; I += 64) zz[I] = 0;
        }

        // ---- projection epilogue: 16-row A-tile covers both b's ----
        {
            int r = wave * 16 + (lane & 15);
            f32x4 ap = {0.f, 0.f, 0.f, 0.f};
#pragma unroll
            for (int ks = 0; ks < 8; ++ks) {
                bf16x8 af = *(const bf16x8*)
                    &S_lds[r * 256 + (((ks * 4 + kg + r) & 31) << 3)];
                ap = __builtin_amdgcn_mfma_f32_16x16x32_bf16(af, bfr[ks], ap, 0, 0, 0);
            }
            int o = lane & 15;
            int b = b0 + (kg >> 1);
            *(float4*)(out + (((size_t)(b * 16 + o)) << 14) + s0 + ((kg & 1) << 2)) =
                make_float4(ap[0], ap[1], ap[2], ap[3]);
        }
    }
}

// ---------------------------------------------------------------------------
extern "C" void kernel_launch(void* const* d_in, const int* in_sizes, int n_in,
                              void* d_out, int out_size, void* d_ws, size_t ws_size,
                              hipStream_t stream) {
    const float* pin  = (const float*)d_in[0];
    const float* pout = (const float*)d_in[1];
    const float* wts  = (const float*)d_in[2];
    const float* feat = (const float*)d_in[3];
    const int*   ei   = (const int*)d_in[4];
    const float* W0   = (const float*)d_in[5];
    const float* W1   = (const float*)d_in[6];
    const float* W2   = (const float*)d_in[7];
    const float* W3   = (const float*)d_in[8];
    const float* W4   = (const float*)d_in[9];
    const float* W5   = (const float*)d_in[10];
    float* out = (float*)d_out;

    u16* ftb    = (u16*)d_ws;                             // 4,194,304 B
    u16* hB     = ftb + (size_t)N_IN * 128;               // 9,600,000 B
    int* segoff = (int*)(hB + (size_t)NCHK * 512 + 64);   // 65,552 B
    u16* Bfrag  = (u16*)(segoff + 16388);                 // 8,192 B

    k_front<<<MLPB + TRB + SETB, 256, 0, stream>>>(
        pin, pout, wts, ei, W0, W1, W2, W3, W4, W5, feat,
        ftb, hB, segoff, Bfrag);
    k_gather<<<GRID_G, 256, 0, stream>>>(ei, ftb, hB, segoff, Bfrag, out);
}

// Round 26
// 49.139 us; speedup vs baseline: 1.0932x; 1.0016x over previous
//
#include <hip/hip_runtime.h>

#define N_IN   16384
#define N_OUT  16384
#define NE     300000
#define SEGS   8           // segments per gather window
#define NWIN   (N_OUT / SEGS)
#define GRID_G 768         // persistent gather grid (3 blocks/CU)
#define BKG    136         // u16 stride per k-group in stage tile (128 + 8 pad)
#define BSTR   544         // u16 per b per (single) buffer = 4 * BKG
#define SROW   256         // u16 per S_lds row (swizzled, no pad)
#define NCHK   9375        // NE / 32 exactly

// k_front block roles
#define MLPB   586
#define TRB    1024
#define SETB   80

typedef unsigned int   u32;
typedef unsigned short u16;
typedef __attribute__((ext_vector_type(4))) float f32x4;
typedef __attribute__((ext_vector_type(8))) short bf16x8;

// round-to-nearest-even fp32 -> bf16 bits
__device__ __forceinline__ u16 f2bf(float x) {
    union { float f; u32 u; } v; v.f = x;
    u32 r = v.u + 0x7fffu + ((v.u >> 16) & 1u);
    return (u16)(r >> 16);
}

__device__ __forceinline__ float fast_sin(float t) {
    float r;
    asm("v_sin_f32 %0, %1" : "=v"(r) : "v"(t * 0.15915494309189535f));
    return r;
}

// ---------------------------------------------------------------------------
// Kernel 1: fused front end (verified, unchanged).
// ---------------------------------------------------------------------------
__global__ __launch_bounds__(256) void k_front(
        const float* __restrict__ pin, const float* __restrict__ pout,
        const float* __restrict__ wts, const int* __restrict__ ei,
        const float* __restrict__ W0, const float* __restrict__ W1,
        const float* __restrict__ W2, const float* __restrict__ W3,
        const float* __restrict__ W4, const float* __restrict__ W5,
        const float* __restrict__ feat,
        u16* __restrict__ ftb, u16* __restrict__ hB,
        int* __restrict__ segoff, u16* __restrict__ Bfrag) {
    __shared__ float tile[32][33];
    int tid = threadIdx.x, bid = blockIdx.x;

    if (bid < MLPB) {
        int e0 = (bid * 256 + tid) * 2;
        if (e0 >= NE) return;
        int4 q = *(const int4*)(ei + e0 * 2);   // (out0,in0,out1,in1)
        float2 po0 = ((const float2*)pout)[q.x];
        float2 pi0 = ((const float2*)pin)[q.y];
        float2 po1 = ((const float2*)pout)[q.z];
        float2 pi1 = ((const float2*)pin)[q.w];
        float x0 = po0.x - pi0.x, y0 = po0.y - pi0.y;
        float x1 = po1.x - pi1.x, y1 = po1.y - pi1.y;

        float h0[16], h1[16];
#pragma unroll
        for (int j = 0; j < 16; ++j) {
            float wa = W0[j], wb = W0[16 + j];          // uniform -> s_load
            h0[j] = fast_sin(x0 * wa + y0 * wb);
            h1[j] = fast_sin(x1 * wa + y1 * wb);
        }
#pragma unroll
        for (int L = 0; L < 4; ++L) {
            const float* W = (L == 0) ? W1 : (L == 1) ? W2 : (L == 2) ? W3 : W4;
            float n0[16], n1[16];
#pragma unroll
            for (int j = 0; j < 16; ++j) {
                float a0 = 0.f, a1 = 0.f;
#pragma unroll
                for (int i = 0; i < 16; ++i) {
                    float w = W[i * 16 + j];            // uniform -> s_load
                    a0 = fmaf(h0[i], w, a0);
                    a1 = fmaf(h1[i], w, a1);
                }
                n0[j] = fast_sin(a0); n1[j] = fast_sin(a1);
            }
#pragma unroll
            for (int j = 0; j < 16; ++j) { h0[j] = n0[j]; h1[j] = n1[j]; }
        }
        float we0 = wts[q.y], we1 = wts[q.w];
        u16* hp = hB + ((size_t)(e0 >> 5)) * 512 + (e0 & 31);
#pragma unroll
        for (int j = 0; j < 16; ++j) {
            u32 pk = (u32)f2bf(we0 * h0[j]) | ((u32)f2bf(we1 * h1[j]) << 16);
            *(u32*)(hp + j * 32) = pk;
        }
    } else if (bid < MLPB + TRB) {
        int jb = (bid - MLPB) * 2;
        int tx = tid & 31, ty = tid >> 5;
#pragma unroll
        for (int t = 0; t < 2; ++t) {
            int job = jb + t;
            int n0 = (job & 511) * 32, c0 = (job >> 9) * 32;
#pragma unroll
            for (int k = 0; k < 4; ++k)
                tile[ty + k * 8][tx] = feat[(size_t)(c0 + ty + k * 8) * N_IN + n0 + tx];
            __syncthreads();
#pragma unroll
            for (int k = 0; k < 4; ++k)
                ftb[(size_t)(n0 + ty + k * 8) * 128 + c0 + tx] = f2bf(tile[tx][ty + k * 8]);
            __syncthreads();
        }
    } else {
        int g = (bid - MLPB - TRB) * 256 + tid;
        if (g <= N_OUT) {
            if (g == N_OUT) segoff[g] = NE;
            else {
                int lo = 0, hi = NE;
                while (lo < hi) { int m = (lo + hi) >> 1; if (ei[2 * m] < g) lo = m + 1; else hi = m; }
                segoff[g] = lo;
            }
        }
        if (g < 4096) {
            int ks = g >> 9, rem = g & 511, l = rem >> 3, e = rem & 7;
            int k = ks * 32 + ((l >> 4) << 3) + e;
            int o = l & 15;
            Bfrag[g] = f2bf(W5[(k >> 4) * 256 + ((k & 15) << 4) + o]);
        }
    }
}

// ---------------------------------------------------------------------------
// Kernel 2: fused MFMA gather + projection. R26 = R23/R25 compact body +
// CROSS-WINDOW PREFETCH: next window's segoff issued at window start (hides
// under chunk loop); next window's chunk-0 ei issued before the epilogue
// (hides under epilogue MFMAs). All data math identical to R25.
// ---------------------------------------------------------------------------
#define EIW(IA, IB, BSE) do {                                             \
    int g_ = (BSE) + 2 * pr; g_ = g_ <= NE - 2 ? g_ : NE - 2;             \
    int4 q_ = *(const int4*)(ei + 2 * g_); IA = q_.y; IB = q_.w; } while (0)

#define FTW(FA, FB, IA, IB) do {                                          \
    FA = ftb4[(size_t)(u32)(IA) * 16 + oct];                              \
    FB = ftb4[(size_t)(u32)(IB) * 16 + oct]; } while (0)

#define BQW(BQ, BSE) do {                                                 \
    int ch_ = (BSE) >> 5; ch_ = ch_ <= NCHK - 1 ? ch_ : NCHK - 1;         \
    BQ = *(const bf16x8*)(hB + (size_t)ch_ * 512 + (j << 5) + (kg << 3)); } while (0)

// v_perm_b32 pack (R23-verified)
#define STGW(FA, FB) do {                                                 \
    u32 aw_[4] = {FA.x, FA.y, FA.z, FA.w};                                \
    u32 bw_[4] = {FB.x, FB.y, FB.z, FB.w};                                \
    int wb_ = bloc * BSTR + (pr >> 2) * BKG + 2 * (pr & 3);               \
    _Pragma("unroll")                                                     \
    for (int h_ = 0; h_ < 4; ++h_) {                                      \
        u32 lo_ = __builtin_amdgcn_perm(bw_[h_], aw_[h_], 0x05040100u);   \
        u32 hi_ = __builtin_amdgcn_perm(bw_[h_], aw_[h_], 0x07060302u);   \
        *(u32*)&stW[wb_ + (ibase + 2 * h_) * 8] = lo_;                    \
        *(u32*)&stW[wb_ + (ibase + 2 * h_ + 1) * 8] = hi_;                \
    } } while (0)

// always-masked PIECE (runtime bounds)
#define PIECEM(KLO, KHI) do {                                             \
    bf16x8 bm_;                                                           \
    _Pragma("unroll")                                                     \
    for (int e_ = 0; e_ < 8; ++e_) {                                      \
        int k_ = kg * 8 + e_;                                             \
        bm_[e_] = (k_ >= (KLO) && k_ < (KHI)) ? bqC[e_] : (short)0;       \
    }                                                                     \
    acc0 = __builtin_amdgcn_mfma_f32_16x16x32_bf16(a0, bm_, acc0, 0, 0, 0); \
    acc1 = __builtin_amdgcn_mfma_f32_16x16x32_bf16(a1, bm_, acc1, 0, 0, 0); \
} while (0)

// swizzled DUMP (verified): chunk c = j*2+(kg>>1); phys = (c+row)&31
#define DUMP(SS) do {                                                     \
    int c_ = j * 2 + (kg >> 1);                                           \
    int r0_ = b0 * SEGS + (SS);                                           \
    int r1_ = r0_ + SEGS;                                                 \
    u32 l0_ = (u32)f2bf(acc0[0]) | ((u32)f2bf(acc0[1]) << 16);            \
    u32 l1_ = (u32)f2bf(acc0[2]) | ((u32)f2bf(acc0[3]) << 16);            \
    *(uint2*)&S_lds[r0_ * 256 + (((c_ + r0_) & 31) << 3) + ((kg & 1) << 2)] = \
        make_uint2(l0_, l1_);                                             \
    u32 l2_ = (u32)f2bf(acc1[0]) | ((u32)f2bf(acc1[1]) << 16);            \
    u32 l3_ = (u32)f2bf(acc1[2]) | ((u32)f2bf(acc1[3]) << 16);            \
    *(uint2*)&S_lds[r1_ * 256 + (((c_ + r1_) & 31) << 3) + ((kg & 1) << 2)] = \
        make_uint2(l2_, l3_);                                             \
    acc0 = (f32x4){0.f, 0.f, 0.f, 0.f}; acc1 = (f32x4){0.f, 0.f, 0.f, 0.f}; \
} while (0)

__global__ __launch_bounds__(256, 3) void k_gather(
        const int* __restrict__ ei, const u16* __restrict__ ftb,
        const u16* __restrict__ hB, const int* __restrict__ segoff,
        const u16* __restrict__ Bfrag, float* __restrict__ out)
{
    __shared__ __align__(16) u16 stA[4 * 2 * BSTR];      //  8704 B (single buf)
    __shared__ __align__(16) u16 S_lds[8 * SEGS * SROW]; // 32768 B (swizzled)

    int tid = threadIdx.x, lane = tid & 63, wave = tid >> 6;
    int b0 = wave * 2;
    int pr = lane >> 2, c4 = lane & 3;
    int bloc = c4 >> 1, ibase = (c4 & 1) * 8;
    int oct = b0 * 2 + c4;
    int j = lane & 15, kg = lane >> 4;
    int soff = (lane <= SEGS ? lane : SEGS);
    u16* stW = stA + wave * (2 * BSTR);
    const uint4* ftb4 = (const uint4*)ftb;

    // proj B-fragments hoisted across all windows
    bf16x8 bfr[8];
#pragma unroll
    for (int ks = 0; ks < 8; ++ks)
        bfr[ks] = *(const bf16x8*)(Bfrag + ks * 512 + lane * 8);

    // ---- first-window prologue preload ----
    int segv = segoff[blockIdx.x * SEGS + soff];
    int e0 = __shfl(segv, 0);
    int base0 = e0 & ~31;
    int eiPA, eiPB;                         // next-chunk0 ei, preloaded
    EIW(eiPA, eiPB, base0);

    for (int w = blockIdx.x; w < NWIN; w += GRID_G) {
        int s0 = w * SEGS;
        int e1 = __shfl(segv, SEGS);
        int nc = (e1 - base0 + 31) >> 5;

        // issue NEXT window's segoff load now (hides under chunk loop)
        int wn = w + GRID_G;
        int segvN = segoff[(wn < NWIN ? wn * SEGS : 0) + soff];

        f32x4 acc0 = {0.f, 0.f, 0.f, 0.f}, acc1 = {0.f, 0.f, 0.f, 0.f};

        if (nc > 0) {
            int eiA, eiB;
            uint4 faA, fbA, faB, fbB;
            bf16x8 bqC, bqN, bqL;
            // prologue: chunk0 ei is ALREADY in eiPA/eiPB
            FTW(faB, fbB, eiPA, eiPB);
            BQW(bqC, base0);
            EIW(eiA, eiB, base0 + 32);   FTW(faA, fbA, eiA, eiB);
            BQW(bqN, base0 + 32);
            STGW(faB, fbB);                           // stage chunk 0
            EIW(eiA, eiB, base0 + 64);   FTW(faB, fbB, eiA, eiB);
            BQW(bqL, base0 + 64);
            EIW(eiA, eiB, base0 + 96);

            int s = 0, klo = e0 - base0;
#pragma unroll 1
            for (int c = 0; c < nc; ++c) {
                int base_ = base0 + 32 * c, ce_ = base_ + 32;
                bf16x8 a0 = *(const bf16x8*)&stW[(lane >> 4) * BKG + (lane & 15) * 8];
                bf16x8 a1 = *(const bf16x8*)&stW[BSTR + (lane >> 4) * BKG + (lane & 15) * 8];
                STGW(faA, fbA);                  // stage chunk c+1 (after reads)
                FTW(faA, fbA, eiA, eiB);         // load chunk c+3 -> A-set
                int eiA2, eiB2; EIW(eiA2, eiB2, base_ + 128);
                bf16x8 bqT; BQW(bqT, base_ + 96);

                // dynamic segment sweep
                int nxt = __shfl(segv, s + 1 <= SEGS ? s + 1 : SEGS);
                while (s < SEGS && nxt <= ce_) {
                    int khi = nxt - base_;
                    if (khi > klo) PIECEM(klo, khi);
                    DUMP(s);
                    ++s; klo = khi;
                    nxt = __shfl(segv, s + 1 <= SEGS ? s + 1 : SEGS);
                }
                if (s < SEGS && klo < 32) PIECEM(klo, 32);
                klo = 0;

                // rotate register sets (A<->B) and pipeline regs
                uint4 t_;
                t_ = faA; faA = faB; faB = t_;
                t_ = fbA; fbA = fbB; fbB = t_;
                bqC = bqN; bqN = bqL; bqL = bqT;
                eiA = eiA2; eiB = eiB2;
            }
        } else {
            // zero this wave's 16 S rows (both b's)
            u32* zz = (u32*)&S_lds[wave * 4096];
            for (int I = lane; I < 2048; I += 64) zz[I] = 0;
        }

        // preload NEXT window's chunk0 ei (hides under the epilogue MFMAs)
        int e0N = __shfl(segvN, 0);
        int base0N = e0N & ~31;
        EIW(eiPA, eiPB, base0N);

        // ---- projection epilogue (verified): 16-row A-tile, both b's ----
        {
            int r = wave * 16 + (lane & 15);
            f32x4 ap = {0.f, 0.f, 0.f, 0.f};
#pragma unroll
            for (int ks = 0; ks < 8; ++ks) {
                bf16x8 af = *(const bf16x8*)
                    &S_lds[r * 256 + (((ks * 4 + kg + r) & 31) << 3)];
                ap = __builtin_amdgcn_mfma_f32_16x16x32_bf16(af, bfr[ks], ap, 0, 0, 0);
            }
            int o = lane & 15;
            int b = b0 + (kg >> 1);
            *(float4*)(out + (((size_t)(b * 16 + o)) << 14) + s0 + ((kg & 1) << 2)) =
                make_float4(ap[0], ap[1], ap[2], ap[3]);
        }

        // rotate window state
        segv = segvN; e0 = e0N; base0 = base0N;
    }
}

// ---------------------------------------------------------------------------
extern "C" void kernel_launch(void* const* d_in, const int* in_sizes, int n_in,
                              void* d_out, int out_size, void* d_ws, size_t ws_size,
                              hipStream_t stream) {
    const float* pin  = (const float*)d_in[0];
    const float* pout = (const float*)d_in[1];
    const float* wts  = (const float*)d_in[2];
    const float* feat = (const float*)d_in[3];
    const int*   ei   = (const int*)d_in[4];
    const float* W0   = (const float*)d_in[5];
    const float* W1   = (const float*)d_in[6];
    const float* W2   = (const float*)d_in[7];
    const float* W3   = (const float*)d_in[8];
    const float* W4   = (const float*)d_in[9];
    const float* W5   = (const float*)d_in[10];
    float* out = (float*)d_out;

    u16* ftb    = (u16*)d_ws;                             // 4,194,304 B
    u16* hB     = ftb + (size_t)N_IN * 128;               // 9,600,000 B
    int* segoff = (int*)(hB + (size_t)NCHK * 512 + 64);   // 65,552 B
    u16* Bfrag  = (u16*)(segoff + 16388);                 // 8,192 B

    k_front<<<MLPB + TRB + SETB, 256, 0, stream>>>(
        pin, pout, wts, ei, W0, W1, W2, W3, W4, W5, feat,
        ftb, hB, segoff, Bfrag);
    k_gather<<<GRID_G, 256, 0, stream>>>(ei, ftb, hB, segoff, Bfrag, out);
}